// Round 20
// baseline (289.974 us; speedup 1.0000x reference)
//
#include <hip/hip_runtime.h>
#include <math.h>

#define B   32
#define T   50
#define N1  50001
#define D   128
#define KP  16
#define MP  50
#define HID 72
#define BT  (B*T)

typedef __attribute__((ext_vector_type(8))) short short8v;
typedef __attribute__((ext_vector_type(4))) float f32x4;

__device__ __forceinline__ unsigned short f2bf(float x) {
    unsigned u = __float_as_uint(x);
    u += 0x7fffu + ((u >> 16) & 1u);
    return (unsigned short)(u >> 16);
}

// ---------------- helpers ----------------
__device__ __forceinline__ float blockReduceSum128(float val, volatile float* sbuf) {
    // blockDim.x == 128 (2 waves of 64)
    for (int off = 32; off > 0; off >>= 1) val += __shfl_down(val, off, 64);
    __syncthreads();
    if ((threadIdx.x & 63) == 0) sbuf[threadIdx.x >> 6] = val;
    __syncthreads();
    return sbuf[0] + sbuf[1];
}

// ---------------- 1. fused: ProxySelection X2 + Xs/q/k/v ----------------
__global__ void k_fused_emb(const int* __restrict__ session,
                            const int* __restrict__ lengths,
                            const float* __restrict__ I_emb,
                            const float* __restrict__ EP_emb,
                            const float* __restrict__ ES_emb,
                            const float* __restrict__ WP1,
                            const float* __restrict__ WP2,
                            const float* __restrict__ Wq,
                            const float* __restrict__ Wk,
                            const float* __restrict__ Wv,
                            float* __restrict__ X2,
                            float* __restrict__ xs_o, float* __restrict__ q_o,
                            float* __restrict__ k_o, float* __restrict__ v_o) {
    int bt = blockIdx.x; int b = bt / T; int t = bt % T;
    int tid = threadIdx.x;   // 128
    __shared__ __align__(16) float x[D];
    __shared__ __align__(16) float xs[D];
    __shared__ float h[HID];
    int sid = session[bt];
    float ie = I_emb[(size_t)sid * D + tid];
    float xv_ = (sid != 0) ? (ie + EP_emb[(t + MP - T) * D + tid]) : 0.f;
    int es = t + 1 - (T - lengths[b]); if (es < 0) es = 0;
    float xsv = ie + ES_emb[es * D + tid];
    x[tid] = xv_;
    xs[tid] = xsv;
    __syncthreads();
    // q/k/v matvecs (all threads)
    float aq = 0.f, ak = 0.f, av = 0.f;
    {
        const float4* wq4 = (const float4*)(Wq + tid * D);
        const float4* wk4 = (const float4*)(Wk + tid * D);
        const float4* wv4 = (const float4*)(Wv + tid * D);
        const float4* x4  = (const float4*)xs;
        #pragma unroll 8
        for (int k = 0; k < D / 4; ++k) {
            float4 xv = x4[k];
            float4 a = wq4[k], bq = wk4[k], c = wv4[k];
            aq += xv.x * a.x + xv.y * a.y + xv.z * a.z + xv.w * a.w;
            ak += xv.x * bq.x + xv.y * bq.y + xv.z * bq.z + xv.w * bq.w;
            av += xv.x * c.x + xv.y * c.y + xv.z * c.z + xv.w * c.w;
        }
    }
    // WP1 (tid < HID)
    if (tid < HID) {
        float acc = 0.f;
        const float4* w4 = (const float4*)(WP1 + tid * D);
        const float4* x4 = (const float4*)x;
        #pragma unroll 8
        for (int k = 0; k < D / 4; ++k) {
            float4 w = w4[k]; float4 xv = x4[k];
            acc += xv.x * w.x + xv.y * w.y + xv.z * w.z + xv.w * w.w;
        }
        h[tid] = acc > 0.f ? acc : 0.1f * acc;
    }
    xs_o[bt * D + tid] = xsv;
    q_o[bt * D + tid] = aq; k_o[bt * D + tid] = ak; v_o[bt * D + tid] = av;
    __syncthreads();
    if (tid < KP) {
        float acc = 0.f;
        const float* w = WP2 + tid * HID;
        for (int k = 0; k < HID; ++k) acc += h[k] * w[k];
        X2[bt * KP + tid] = acc;
    }
}

// ---------------- 2. softmax head: pi, p_s, v, orthogonal ----------------
__global__ void k_proxy_head(const float* __restrict__ X2,
                             const int* __restrict__ lengths,
                             const int* __restrict__ tau_i,
                             const float* __restrict__ P_emb,
                             const float* __restrict__ V,
                             float* __restrict__ ps_o,
                             float* __restrict__ v_o,
                             float* __restrict__ orth_o) {
    int b = blockIdx.x; int tid = threadIdx.x;   // 128
    __shared__ float pi[KP];
    __shared__ float vn[KP];
    __shared__ float sbuf[2];
    float tau = (float)tau_i[0];
    float lf = (float)lengths[b];
    if (tid < KP) {
        float s = 0.f;
        for (int t = 0; t < T; ++t) s += X2[(b * T + t) * KP + tid];
        pi[tid] = (s / lf) / tau;
    }
    if (tid < KP) {
        float s = 0.f;
        for (int d = 0; d < D; ++d) { float z = V[tid * D + d]; s += z * z; }
        vn[tid] = fmaxf(sqrtf(s), 1e-12f);
    }
    __syncthreads();
    if (tid == 0) {
        float m = pi[0];
        for (int k = 1; k < KP; ++k) m = fmaxf(m, pi[k]);
        float s = 0.f;
        for (int k = 0; k < KP; ++k) { float e = expf(pi[k] - m); pi[k] = e; s += e; }
        for (int k = 0; k < KP; ++k) pi[k] /= s;
    }
    __syncthreads();
    float p = 0.f, vt = 0.f;
    for (int k = 0; k < KP; ++k) {
        p  += pi[k] * P_emb[k * D + tid];
        vt += pi[k] * (V[k * D + tid] / vn[k]);
    }
    float vsq = blockReduceSum128(vt * vt, sbuf);
    float vv = vt / fmaxf(sqrtf(vsq), 1e-12f);
    float psq = blockReduceSum128(p * p, sbuf);
    float dvp = blockReduceSum128(vv * p, sbuf);
    ps_o[b * D + tid] = p;
    v_o[b * D + tid] = vv;
    if (tid == 0) orth_o[b] = fabsf(dvp) / sqrtf(psq);
}

// ---------------- 3. fused: attention + Wo/LN1 + FFN/LN2 + projection -> G16, Fn2 ----------------
__global__ void k_fused_attn(const int* __restrict__ session,
                             const float* __restrict__ q,
                             const float* __restrict__ kk,
                             const float* __restrict__ vv,
                             const float* __restrict__ xs,
                             const float* __restrict__ Wo,
                             const float* __restrict__ g1, const float* __restrict__ b1,
                             const float* __restrict__ FF1, const float* __restrict__ FF2,
                             const float* __restrict__ g2, const float* __restrict__ b2,
                             const float* __restrict__ ps, const float* __restrict__ v,
                             short* __restrict__ G16, float* __restrict__ Fn2) {
    int bt = blockIdx.x; int b = bt / T; int t = bt % T;
    int tid = threadIdx.x;  // 128
    __shared__ __align__(16) float qs[D];
    __shared__ __align__(16) float buf1[D];
    __shared__ __align__(16) float buf2[D];
    __shared__ float attn[64];
    __shared__ float sbuf[2];
    // --- attention ---
    qs[tid] = q[bt * D + tid];
    __syncthreads();
    if (tid < T) {
        int s = tid;
        bool allowed = (s == 0) || ((s <= t) && (session[b * T + s] != 0));
        float sc = -1e9f;
        if (allowed) {
            float a = 0.f;
            const float4* kr = (const float4*)(kk + (size_t)(b * T + s) * D);
            const float4* q4 = (const float4*)qs;
            #pragma unroll 8
            for (int d = 0; d < D / 4; ++d) {
                float4 kv = kr[d]; float4 qv = q4[d];
                a += qv.x * kv.x + qv.y * kv.y + qv.z * kv.z + qv.w * kv.w;
            }
            sc = a * 0.088388347648318447f;  // 1/sqrt(128)
        }
        attn[s] = sc;
    }
    __syncthreads();
    if (tid < 64) {
        float vsc = (tid < T) ? attn[tid] : -1e30f;
        float m = vsc;
        for (int off = 32; off > 0; off >>= 1) m = fmaxf(m, __shfl_xor(m, off, 64));
        float e = (tid < T) ? expf(vsc - m) : 0.f;
        float ssum = e;
        for (int off = 32; off > 0; off >>= 1) ssum += __shfl_xor(ssum, off, 64);
        if (tid < T) attn[tid] = e / ssum;
    }
    __syncthreads();
    float acc = 0.f;
    for (int s = 0; s < T; ++s) acc += attn[s] * vv[(size_t)(b * T + s) * D + tid];
    // --- Wo + residual + LN1 ---
    buf1[tid] = acc;
    __syncthreads();
    float a = 0.f;
    {
        const float4* w4 = (const float4*)(Wo + tid * D);
        const float4* h4 = (const float4*)buf1;
        #pragma unroll 8
        for (int k = 0; k < D / 4; ++k) {
            float4 w = w4[k]; float4 hv = h4[k];
            a += hv.x * w.x + hv.y * w.y + hv.z * w.z + hv.w * w.w;
        }
    }
    float x1 = a + xs[bt * D + tid];
    float mean = blockReduceSum128(x1, sbuf) * (1.f / D);
    float dx = x1 - mean;
    float var = blockReduceSum128(dx * dx, sbuf) * (1.f / D);
    float hx = (dx * rsqrtf(var + 1e-6f) * g1[tid] + b1[tid]) * ((session[bt] != 0) ? 1.f : 0.f);
    // --- FFN + LN2 ---
    buf2[tid] = hx;
    __syncthreads();
    float a1 = 0.f;
    {
        const float4* w4 = (const float4*)(FF1 + tid * D);
        const float4* h4 = (const float4*)buf2;
        #pragma unroll 8
        for (int k = 0; k < D / 4; ++k) {
            float4 w = w4[k]; float4 hv = h4[k];
            a1 += hv.x * w.x + hv.y * w.y + hv.z * w.z + hv.w * w.w;
        }
    }
    __syncthreads();
    buf1[tid] = fmaxf(a1, 0.f);
    __syncthreads();
    float f = 0.f;
    {
        const float4* w4 = (const float4*)(FF2 + tid * D);
        const float4* t4 = (const float4*)buf1;
        #pragma unroll 8
        for (int k = 0; k < D / 4; ++k) {
            float4 w = w4[k]; float4 tv = t4[k];
            f += tv.x * w.x + tv.y * w.y + tv.z * w.z + tv.w * w.w;
        }
    }
    float x2 = f + hx;
    float mean2 = blockReduceSum128(x2, sbuf) * (1.f / D);
    float dx2 = x2 - mean2;
    float var2 = blockReduceSum128(dx2 * dx2, sbuf) * (1.f / D);
    float ss = dx2 * rsqrtf(var2 + 1e-6f) * g2[tid] + b2[tid];
    ss *= (session[bt] != 0) ? 1.f : 0.f;
    // --- projection -> G, Fn2 ---
    float vb = v[b * D + tid];
    float vs = blockReduceSum128(vb * ss, sbuf);
    float ssp = ss - vb * vs;
    float Fd = ps[b * D + tid] + ssp;
    float Fv = blockReduceSum128(Fd * vb, sbuf);
    float Gd = Fd - Fv * vb;
    float fn2 = blockReduceSum128(Fd * Fd, sbuf);
    G16[bt * D + tid] = (short)f2bf(Gd);
    if (tid == 0) Fn2[bt] = fn2;
}

#define LDK 136   // 128 + 8 pad shorts -> 272B row stride, balanced bank groups on ds_read_b128

// ---------------- 4. per-item stats via MFMA + I->bf16 spill ----------------
__global__ __launch_bounds__(256) void k_item_mfma(const float* __restrict__ I,
                                                   const float* __restrict__ v,
                                                   float* __restrict__ In2pb,
                                                   unsigned short* __restrict__ I16) {
    __shared__ __align__(16) short Is[64][LDK];
    __shared__ __align__(16) short Vs[32][LDK];
    __shared__ float sq[64][4];
    __shared__ float in2[64];
    int n0 = blockIdx.x * 64;
    int tid = threadIdx.x;   // 256
    {
        int vr = tid >> 3;
        int vc = (tid & 7) * 16;
        const float4* src = (const float4*)&v[vr * D + vc];
        #pragma unroll
        for (int s = 0; s < 4; ++s) {
            float4 f = src[s];
            ushort4 u;
            u.x = f2bf(f.x); u.y = f2bf(f.y); u.z = f2bf(f.z); u.w = f2bf(f.w);
            *(ushort4*)&Vs[vr][vc + s * 4] = u;
        }
    }
    {
        int r = tid >> 2;
        int qq = tid & 3;
        int n = n0 + r;
        float ss = 0.f;
        if (n < N1) {
            const float4* src = (const float4*)&I[(size_t)n * D + qq * 32];
            #pragma unroll
            for (int s = 0; s < 8; ++s) {
                float4 f = src[s];
                ss += f.x * f.x + f.y * f.y + f.z * f.z + f.w * f.w;
                ushort4 u;
                u.x = f2bf(f.x); u.y = f2bf(f.y); u.z = f2bf(f.z); u.w = f2bf(f.w);
                *(ushort4*)&Is[r][qq * 32 + s * 4] = u;
                *(ushort4*)&I16[(size_t)n * D + qq * 32 + s * 4] = u;
            }
        } else {
            #pragma unroll
            for (int s = 0; s < 8; ++s)
                *(ushort4*)&Is[r][qq * 32 + s * 4] = make_ushort4(0, 0, 0, 0);
        }
        sq[r][qq] = ss;
    }
    __syncthreads();
    if (tid < 64) in2[tid] = sq[tid][0] + sq[tid][1] + sq[tid][2] + sq[tid][3];
    __syncthreads();
    int w = tid >> 6, l = tid & 63, lr = l & 15, lg = l >> 4;
    f32x4 acc[2] = {{0.f,0.f,0.f,0.f},{0.f,0.f,0.f,0.f}};
    short8v af[4];
    #pragma unroll
    for (int ks = 0; ks < 4; ++ks)
        af[ks] = *(const short8v*)&Is[w * 16 + lr][ks * 32 + lg * 8];
    #pragma unroll
    for (int nt = 0; nt < 2; ++nt) {
        #pragma unroll
        for (int ks = 0; ks < 4; ++ks) {
            short8v bf = *(const short8v*)&Vs[nt * 16 + lr][ks * 32 + lg * 8];
            acc[nt] = __builtin_amdgcn_mfma_f32_16x16x32_bf16(af[ks], bf, acc[nt], 0, 0, 0);
        }
    }
    #pragma unroll
    for (int nt = 0; nt < 2; ++nt) {
        int b = nt * 16 + lr;
        #pragma unroll
        for (int i = 0; i < 4; ++i) {
            int item = w * 16 + lg * 4 + i;
            int n = n0 + item;
            if (n < N1) {
                float dvi = acc[nt][i];
                In2pb[(size_t)b * N1 + n] = in2[item] - dvi * dvi;
            }
        }
    }
}

// ---------------- 5. dist kernel: 64-col stripe per block, stage-once, 6 blocks/CU ----------------
// out[row,col] = Fn2[row] + In2pb[b][col] - 2 * (G_row . I_col)
// r11 structure with BN 128->64: LDS 25.6 KB -> 6 blocks/CU (24 waves/CU, ~75% occ)
// to hide the L2-A-load -> MFMA -> store serial chain. Fetch stays stage-once-minimal.
#define BN 64
__global__ __launch_bounds__(256) void k_dist_mfma(const short* __restrict__ G16,
                                                   const unsigned short* __restrict__ I16,
                                                   const float* __restrict__ Fn2,
                                                   const float* __restrict__ In2pb,
                                                   float* __restrict__ out) {
    __shared__ __align__(16) short Bs[BN][LDK];   // 17408 B
    __shared__ float in2s[B][BN];                 // 8192 B  -> 25600 total
    int n0  = blockIdx.x * BN;                    // col stripe
    int rt0 = (blockIdx.y == 0) ? 0 : 7;          // row tiles [0,7) / [7,13)
    int rt1 = (blockIdx.y == 0) ? 7 : 13;
    int tid = threadIdx.x;
    // stage I16 stripe: 64 items x 128 shorts (64B per thread)
    {
        int r  = tid >> 2;           // 0..63
        int c0 = (tid & 3) * 32;     // short offset
        int n = n0 + r;
        #pragma unroll
        for (int s = 0; s < 4; ++s) {
            short8v bv = {};
            if (n < N1) bv = *(const short8v*)&I16[(size_t)n * D + c0 + s * 8];
            *(short8v*)&Bs[r][c0 + s * 8] = bv;
        }
    }
    // stage In2pb slice: all 32 b x 64 cols
    for (int i = tid; i < B * BN; i += 256) {
        int bb = i >> 6;
        int cl = i & (BN - 1);
        int col = n0 + cl;
        in2s[bb][cl] = (col < N1) ? In2pb[(size_t)bb * N1 + col] : 0.f;
    }
    __syncthreads();
    int w  = tid >> 6;
    int l  = tid & 63;
    int lr = l & 15;
    int lg = l >> 4;
    for (int rt = rt0; rt < rt1; ++rt) {
        int bt0 = rt * 128;
        #pragma unroll
        for (int mi = 0; mi < 2; ++mi) {
            int rbase = bt0 + w * 32 + mi * 16;
            short8v af[4];
            const short* arow = &G16[(size_t)(rbase + lr) * D];
            #pragma unroll
            for (int ks = 0; ks < 4; ++ks)
                af[ks] = *(const short8v*)&arow[ks * 32 + lg * 8];
            f32x4 acc[4];
            #pragma unroll
            for (int nt = 0; nt < 4; ++nt) acc[nt] = (f32x4){0.f, 0.f, 0.f, 0.f};
            #pragma unroll
            for (int nt = 0; nt < 4; ++nt) {
                #pragma unroll
                for (int ks = 0; ks < 4; ++ks) {
                    short8v bf = *(const short8v*)&Bs[nt * 16 + lr][ks * 32 + lg * 8];
                    acc[nt] = __builtin_amdgcn_mfma_f32_16x16x32_bf16(af[ks], bf, acc[nt], 0, 0, 0);
                }
            }
            int rb = rbase + lg * 4;
            if (rb < BT) {
                float4 fn4 = *(const float4*)&Fn2[rb];
                float fnv[4] = {fn4.x, fn4.y, fn4.z, fn4.w};
                #pragma unroll
                for (int i = 0; i < 4; ++i) {
                    int row = rb + i;
                    int bb = row / T;
                    float* orow = out + (size_t)row * N1 + n0;
                    #pragma unroll
                    for (int nt = 0; nt < 4; ++nt) {
                        int cl = nt * 16 + lr;
                        if (n0 + cl < N1) orow[cl] = fnv[i] + in2s[bb][cl] - 2.f * acc[nt][i];
                    }
                }
            }
        }
    }
}

// ---------------- launch ----------------
extern "C" void kernel_launch(void* const* d_in, const int* in_sizes, int n_in,
                              void* d_out, int out_size, void* d_ws, size_t ws_size,
                              hipStream_t stream) {
    const int*   session = (const int*)d_in[0];
    const int*   lengths = (const int*)d_in[1];
    const int*   tau     = (const int*)d_in[2];
    const float* I_emb   = (const float*)d_in[5];
    const float* P_emb   = (const float*)d_in[6];
    const float* EP      = (const float*)d_in[7];
    const float* ES      = (const float*)d_in[8];
    const float* V       = (const float*)d_in[9];
    const float* WP1     = (const float*)d_in[10];
    const float* WP2     = (const float*)d_in[11];
    const float* Wq      = (const float*)d_in[12];
    const float* Wk      = (const float*)d_in[13];
    const float* Wv      = (const float*)d_in[14];
    const float* Wo      = (const float*)d_in[15];
    const float* FF1     = (const float*)d_in[16];
    const float* FF2     = (const float*)d_in[17];
    const float* g1      = (const float*)d_in[18];
    const float* b1      = (const float*)d_in[19];
    const float* g2      = (const float*)d_in[20];
    const float* b2      = (const float*)d_in[21];
    float* out = (float*)d_out;
    float* ws  = (float*)d_ws;

    // workspace layout (floats)
    float* wsX2   = ws;                       // 25600
    float* wsPs   = wsX2 + 25600;             // 4096
    float* wsV    = wsPs + 4096;              // 4096
    float* wsXs   = wsV + 4096;               // 204800 each
    float* wsQ    = wsXs + 204800;
    float* wsK    = wsQ + 204800;
    float* wsVv   = wsK + 204800;
    float* wsFn2  = wsVv + 204800;            // 1600
    float* wsIn2  = wsFn2 + 1600;             // 32*50001 = 1600032
    short* wsG16  = (short*)(wsIn2 + 1600032);            // padded to 1664 rows (212992 shorts)
    unsigned short* wsI16 = (unsigned short*)(wsG16 + 212992);  // 50001*128 shorts

    float* orth_out = out + (size_t)BT * N1;

    k_fused_emb <<<BT, 128, 0, stream>>>(session, lengths, I_emb, EP, ES,
                                         WP1, WP2, Wq, Wk, Wv,
                                         wsX2, wsXs, wsQ, wsK, wsVv);
    k_proxy_head<<<B, 128, 0, stream>>>(wsX2, lengths, tau, P_emb, V, wsPs, wsV, orth_out);
    k_fused_attn<<<BT, 128, 0, stream>>>(session, wsQ, wsK, wsVv, wsXs,
                                         Wo, g1, b1, FF1, FF2, g2, b2,
                                         wsPs, wsV, wsG16, wsFn2);
    k_item_mfma <<<(N1 + 63) / 64, 256, 0, stream>>>(I_emb, wsV, wsIn2, wsI16);
    dim3 gdist((N1 + BN - 1) / BN, 2);
    k_dist_mfma <<<gdist, 256, 0, stream>>>(wsG16, wsI16, wsFn2, wsIn2, out);
}

// Round 21
// 250.805 us; speedup vs baseline: 1.1562x; 1.1562x over previous
//
#include <hip/hip_runtime.h>
#include <math.h>

#define B   32
#define T   50
#define N1  50001
#define D   128
#define KP  16
#define MP  50
#define HID 72
#define BT  (B*T)

typedef __attribute__((ext_vector_type(8))) short short8v;
typedef __attribute__((ext_vector_type(4))) float f32x4;

__device__ __forceinline__ unsigned short f2bf(float x) {
    unsigned u = __float_as_uint(x);
    u += 0x7fffu + ((u >> 16) & 1u);
    return (unsigned short)(u >> 16);
}

// ---------------- helpers ----------------
__device__ __forceinline__ float blockReduceSum128(float val, volatile float* sbuf) {
    // blockDim.x == 128 (2 waves of 64)
    for (int off = 32; off > 0; off >>= 1) val += __shfl_down(val, off, 64);
    __syncthreads();
    if ((threadIdx.x & 63) == 0) sbuf[threadIdx.x >> 6] = val;
    __syncthreads();
    return sbuf[0] + sbuf[1];
}

// ---------------- 1. fused: ProxySelection X2 + Xs/q/k/v ----------------
__global__ void k_fused_emb(const int* __restrict__ session,
                            const int* __restrict__ lengths,
                            const float* __restrict__ I_emb,
                            const float* __restrict__ EP_emb,
                            const float* __restrict__ ES_emb,
                            const float* __restrict__ WP1,
                            const float* __restrict__ WP2,
                            const float* __restrict__ Wq,
                            const float* __restrict__ Wk,
                            const float* __restrict__ Wv,
                            float* __restrict__ X2,
                            float* __restrict__ xs_o, float* __restrict__ q_o,
                            float* __restrict__ k_o, float* __restrict__ v_o) {
    int bt = blockIdx.x; int b = bt / T; int t = bt % T;
    int tid = threadIdx.x;   // 128
    __shared__ __align__(16) float x[D];
    __shared__ __align__(16) float xs[D];
    __shared__ float h[HID];
    int sid = session[bt];
    float ie = I_emb[(size_t)sid * D + tid];
    float xv_ = (sid != 0) ? (ie + EP_emb[(t + MP - T) * D + tid]) : 0.f;
    int es = t + 1 - (T - lengths[b]); if (es < 0) es = 0;
    float xsv = ie + ES_emb[es * D + tid];
    x[tid] = xv_;
    xs[tid] = xsv;
    __syncthreads();
    // q/k/v matvecs (all threads)
    float aq = 0.f, ak = 0.f, av = 0.f;
    {
        const float4* wq4 = (const float4*)(Wq + tid * D);
        const float4* wk4 = (const float4*)(Wk + tid * D);
        const float4* wv4 = (const float4*)(Wv + tid * D);
        const float4* x4  = (const float4*)xs;
        #pragma unroll 8
        for (int k = 0; k < D / 4; ++k) {
            float4 xv = x4[k];
            float4 a = wq4[k], bq = wk4[k], c = wv4[k];
            aq += xv.x * a.x + xv.y * a.y + xv.z * a.z + xv.w * a.w;
            ak += xv.x * bq.x + xv.y * bq.y + xv.z * bq.z + xv.w * bq.w;
            av += xv.x * c.x + xv.y * c.y + xv.z * c.z + xv.w * c.w;
        }
    }
    // WP1 (tid < HID)
    if (tid < HID) {
        float acc = 0.f;
        const float4* w4 = (const float4*)(WP1 + tid * D);
        const float4* x4 = (const float4*)x;
        #pragma unroll 8
        for (int k = 0; k < D / 4; ++k) {
            float4 w = w4[k]; float4 xv = x4[k];
            acc += xv.x * w.x + xv.y * w.y + xv.z * w.z + xv.w * w.w;
        }
        h[tid] = acc > 0.f ? acc : 0.1f * acc;
    }
    xs_o[bt * D + tid] = xsv;
    q_o[bt * D + tid] = aq; k_o[bt * D + tid] = ak; v_o[bt * D + tid] = av;
    __syncthreads();
    if (tid < KP) {
        float acc = 0.f;
        const float* w = WP2 + tid * HID;
        for (int k = 0; k < HID; ++k) acc += h[k] * w[k];
        X2[bt * KP + tid] = acc;
    }
}

// ---------------- 2. softmax head: pi, p_s, v, orthogonal ----------------
__global__ void k_proxy_head(const float* __restrict__ X2,
                             const int* __restrict__ lengths,
                             const int* __restrict__ tau_i,
                             const float* __restrict__ P_emb,
                             const float* __restrict__ V,
                             float* __restrict__ ps_o,
                             float* __restrict__ v_o,
                             float* __restrict__ orth_o) {
    int b = blockIdx.x; int tid = threadIdx.x;   // 128
    __shared__ float pi[KP];
    __shared__ float vn[KP];
    __shared__ float sbuf[2];
    float tau = (float)tau_i[0];
    float lf = (float)lengths[b];
    if (tid < KP) {
        float s = 0.f;
        for (int t = 0; t < T; ++t) s += X2[(b * T + t) * KP + tid];
        pi[tid] = (s / lf) / tau;
    }
    if (tid < KP) {
        float s = 0.f;
        for (int d = 0; d < D; ++d) { float z = V[tid * D + d]; s += z * z; }
        vn[tid] = fmaxf(sqrtf(s), 1e-12f);
    }
    __syncthreads();
    if (tid == 0) {
        float m = pi[0];
        for (int k = 1; k < KP; ++k) m = fmaxf(m, pi[k]);
        float s = 0.f;
        for (int k = 0; k < KP; ++k) { float e = expf(pi[k] - m); pi[k] = e; s += e; }
        for (int k = 0; k < KP; ++k) pi[k] /= s;
    }
    __syncthreads();
    float p = 0.f, vt = 0.f;
    for (int k = 0; k < KP; ++k) {
        p  += pi[k] * P_emb[k * D + tid];
        vt += pi[k] * (V[k * D + tid] / vn[k]);
    }
    float vsq = blockReduceSum128(vt * vt, sbuf);
    float vv = vt / fmaxf(sqrtf(vsq), 1e-12f);
    float psq = blockReduceSum128(p * p, sbuf);
    float dvp = blockReduceSum128(vv * p, sbuf);
    ps_o[b * D + tid] = p;
    v_o[b * D + tid] = vv;
    if (tid == 0) orth_o[b] = fabsf(dvp) / sqrtf(psq);
}

// ---------------- 3. fused: attention + Wo/LN1 + FFN/LN2 + projection -> G16, Fn2 ----------------
__global__ void k_fused_attn(const int* __restrict__ session,
                             const float* __restrict__ q,
                             const float* __restrict__ kk,
                             const float* __restrict__ vv,
                             const float* __restrict__ xs,
                             const float* __restrict__ Wo,
                             const float* __restrict__ g1, const float* __restrict__ b1,
                             const float* __restrict__ FF1, const float* __restrict__ FF2,
                             const float* __restrict__ g2, const float* __restrict__ b2,
                             const float* __restrict__ ps, const float* __restrict__ v,
                             short* __restrict__ G16, float* __restrict__ Fn2) {
    int bt = blockIdx.x; int b = bt / T; int t = bt % T;
    int tid = threadIdx.x;  // 128
    __shared__ __align__(16) float qs[D];
    __shared__ __align__(16) float buf1[D];
    __shared__ __align__(16) float buf2[D];
    __shared__ float attn[64];
    __shared__ float sbuf[2];
    // --- attention ---
    qs[tid] = q[bt * D + tid];
    __syncthreads();
    if (tid < T) {
        int s = tid;
        bool allowed = (s == 0) || ((s <= t) && (session[b * T + s] != 0));
        float sc = -1e9f;
        if (allowed) {
            float a = 0.f;
            const float4* kr = (const float4*)(kk + (size_t)(b * T + s) * D);
            const float4* q4 = (const float4*)qs;
            #pragma unroll 8
            for (int d = 0; d < D / 4; ++d) {
                float4 kv = kr[d]; float4 qv = q4[d];
                a += qv.x * kv.x + qv.y * kv.y + qv.z * kv.z + qv.w * kv.w;
            }
            sc = a * 0.088388347648318447f;  // 1/sqrt(128)
        }
        attn[s] = sc;
    }
    __syncthreads();
    if (tid < 64) {
        float vsc = (tid < T) ? attn[tid] : -1e30f;
        float m = vsc;
        for (int off = 32; off > 0; off >>= 1) m = fmaxf(m, __shfl_xor(m, off, 64));
        float e = (tid < T) ? expf(vsc - m) : 0.f;
        float ssum = e;
        for (int off = 32; off > 0; off >>= 1) ssum += __shfl_xor(ssum, off, 64);
        if (tid < T) attn[tid] = e / ssum;
    }
    __syncthreads();
    float acc = 0.f;
    for (int s = 0; s < T; ++s) acc += attn[s] * vv[(size_t)(b * T + s) * D + tid];
    // --- Wo + residual + LN1 ---
    buf1[tid] = acc;
    __syncthreads();
    float a = 0.f;
    {
        const float4* w4 = (const float4*)(Wo + tid * D);
        const float4* h4 = (const float4*)buf1;
        #pragma unroll 8
        for (int k = 0; k < D / 4; ++k) {
            float4 w = w4[k]; float4 hv = h4[k];
            a += hv.x * w.x + hv.y * w.y + hv.z * w.z + hv.w * w.w;
        }
    }
    float x1 = a + xs[bt * D + tid];
    float mean = blockReduceSum128(x1, sbuf) * (1.f / D);
    float dx = x1 - mean;
    float var = blockReduceSum128(dx * dx, sbuf) * (1.f / D);
    float hx = (dx * rsqrtf(var + 1e-6f) * g1[tid] + b1[tid]) * ((session[bt] != 0) ? 1.f : 0.f);
    // --- FFN + LN2 ---
    buf2[tid] = hx;
    __syncthreads();
    float a1 = 0.f;
    {
        const float4* w4 = (const float4*)(FF1 + tid * D);
        const float4* h4 = (const float4*)buf2;
        #pragma unroll 8
        for (int k = 0; k < D / 4; ++k) {
            float4 w = w4[k]; float4 hv = h4[k];
            a1 += hv.x * w.x + hv.y * w.y + hv.z * w.z + hv.w * w.w;
        }
    }
    __syncthreads();
    buf1[tid] = fmaxf(a1, 0.f);
    __syncthreads();
    float f = 0.f;
    {
        const float4* w4 = (const float4*)(FF2 + tid * D);
        const float4* t4 = (const float4*)buf1;
        #pragma unroll 8
        for (int k = 0; k < D / 4; ++k) {
            float4 w = w4[k]; float4 tv = t4[k];
            f += tv.x * w.x + tv.y * w.y + tv.z * w.z + tv.w * w.w;
        }
    }
    float x2 = f + hx;
    float mean2 = blockReduceSum128(x2, sbuf) * (1.f / D);
    float dx2 = x2 - mean2;
    float var2 = blockReduceSum128(dx2 * dx2, sbuf) * (1.f / D);
    float ss = dx2 * rsqrtf(var2 + 1e-6f) * g2[tid] + b2[tid];
    ss *= (session[bt] != 0) ? 1.f : 0.f;
    // --- projection -> G, Fn2 ---
    float vb = v[b * D + tid];
    float vs = blockReduceSum128(vb * ss, sbuf);
    float ssp = ss - vb * vs;
    float Fd = ps[b * D + tid] + ssp;
    float Fv = blockReduceSum128(Fd * vb, sbuf);
    float Gd = Fd - Fv * vb;
    float fn2 = blockReduceSum128(Fd * Fd, sbuf);
    G16[bt * D + tid] = (short)f2bf(Gd);
    if (tid == 0) Fn2[bt] = fn2;
}

#define LDK 136   // 128 + 8 pad shorts -> 272B row stride, balanced bank groups on ds_read_b128

// ---------------- 4. per-item stats via MFMA + I->bf16 spill ----------------
__global__ __launch_bounds__(256) void k_item_mfma(const float* __restrict__ I,
                                                   const float* __restrict__ v,
                                                   float* __restrict__ In2pb,
                                                   unsigned short* __restrict__ I16) {
    __shared__ __align__(16) short Is[64][LDK];
    __shared__ __align__(16) short Vs[32][LDK];
    __shared__ float sq[64][4];
    __shared__ float in2[64];
    int n0 = blockIdx.x * 64;
    int tid = threadIdx.x;   // 256
    {
        int vr = tid >> 3;
        int vc = (tid & 7) * 16;
        const float4* src = (const float4*)&v[vr * D + vc];
        #pragma unroll
        for (int s = 0; s < 4; ++s) {
            float4 f = src[s];
            ushort4 u;
            u.x = f2bf(f.x); u.y = f2bf(f.y); u.z = f2bf(f.z); u.w = f2bf(f.w);
            *(ushort4*)&Vs[vr][vc + s * 4] = u;
        }
    }
    {
        int r = tid >> 2;
        int qq = tid & 3;
        int n = n0 + r;
        float ss = 0.f;
        if (n < N1) {
            const float4* src = (const float4*)&I[(size_t)n * D + qq * 32];
            #pragma unroll
            for (int s = 0; s < 8; ++s) {
                float4 f = src[s];
                ss += f.x * f.x + f.y * f.y + f.z * f.z + f.w * f.w;
                ushort4 u;
                u.x = f2bf(f.x); u.y = f2bf(f.y); u.z = f2bf(f.z); u.w = f2bf(f.w);
                *(ushort4*)&Is[r][qq * 32 + s * 4] = u;
                *(ushort4*)&I16[(size_t)n * D + qq * 32 + s * 4] = u;
            }
        } else {
            #pragma unroll
            for (int s = 0; s < 8; ++s)
                *(ushort4*)&Is[r][qq * 32 + s * 4] = make_ushort4(0, 0, 0, 0);
        }
        sq[r][qq] = ss;
    }
    __syncthreads();
    if (tid < 64) in2[tid] = sq[tid][0] + sq[tid][1] + sq[tid][2] + sq[tid][3];
    __syncthreads();
    int w = tid >> 6, l = tid & 63, lr = l & 15, lg = l >> 4;
    f32x4 acc[2] = {{0.f,0.f,0.f,0.f},{0.f,0.f,0.f,0.f}};
    short8v af[4];
    #pragma unroll
    for (int ks = 0; ks < 4; ++ks)
        af[ks] = *(const short8v*)&Is[w * 16 + lr][ks * 32 + lg * 8];
    #pragma unroll
    for (int nt = 0; nt < 2; ++nt) {
        #pragma unroll
        for (int ks = 0; ks < 4; ++ks) {
            short8v bf = *(const short8v*)&Vs[nt * 16 + lr][ks * 32 + lg * 8];
            acc[nt] = __builtin_amdgcn_mfma_f32_16x16x32_bf16(af[ks], bf, acc[nt], 0, 0, 0);
        }
    }
    #pragma unroll
    for (int nt = 0; nt < 2; ++nt) {
        int b = nt * 16 + lr;
        #pragma unroll
        for (int i = 0; i < 4; ++i) {
            int item = w * 16 + lg * 4 + i;
            int n = n0 + item;
            if (n < N1) {
                float dvi = acc[nt][i];
                In2pb[(size_t)b * N1 + n] = in2[item] - dvi * dvi;
            }
        }
    }
}

// ---------------- 5. dist kernel: 128-col stripe, 4-way row split, 4 blocks/CU ----------------
// out[row,col] = Fn2[row] + In2pb[b][col] - 2 * (G_row . I_col)
// r11 structure (BN=128, 512B write spans) with y split into 4 row-tile ranges so the
// in2s slice shrinks to the <=11 sessions the range touches: LDS 51.2 -> 40.4 KB
// -> 4 blocks/CU (16 waves, +33% latency hiding). Fetch stays stage-once (~4x I16 = 51 MB).
#define BN 128
#define NB_IN2 11
__global__ __launch_bounds__(256) void k_dist_mfma(const short* __restrict__ G16,
                                                   const unsigned short* __restrict__ I16,
                                                   const float* __restrict__ Fn2,
                                                   const float* __restrict__ In2pb,
                                                   float* __restrict__ out) {
    __shared__ __align__(16) short Bs[BN][LDK];   // 34816 B
    __shared__ float in2s[NB_IN2][BN];            // 5632 B  -> 40448 total, 4 blocks/CU
    const int rtab0[4] = {0, 4, 7, 10};
    const int rtab1[4] = {4, 7, 10, 13};
    int n0  = blockIdx.x * BN;                    // col stripe (fastest)
    int yi  = blockIdx.y;
    int rt0 = rtab0[yi], rt1 = rtab1[yi];
    int b_lo = (rt0 * 128) / T;
    int tid = threadIdx.x;
    // stage I16 stripe: 128 items x 128 shorts (128B per thread)
    {
        int r  = tid >> 1;
        int c0 = (tid & 1) * 64;
        int n = n0 + r;
        #pragma unroll
        for (int s = 0; s < 8; ++s) {
            short8v bv = {};
            if (n < N1) bv = *(const short8v*)&I16[(size_t)n * D + c0 + s * 8];
            *(short8v*)&Bs[r][c0 + s * 8] = bv;
        }
    }
    // stage In2pb slice: NB_IN2 b-rows x 128 cols
    for (int i = tid; i < NB_IN2 * BN; i += 256) {
        int bb = i >> 7;
        int cl = i & (BN - 1);
        int b = b_lo + bb; if (b > B - 1) b = B - 1;
        int col = n0 + cl;
        in2s[bb][cl] = (col < N1) ? In2pb[(size_t)b * N1 + col] : 0.f;
    }
    __syncthreads();
    int w  = tid >> 6;
    int l  = tid & 63;
    int lr = l & 15;
    int lg = l >> 4;
    for (int rt = rt0; rt < rt1; ++rt) {
        int bt0 = rt * 128;
        #pragma unroll
        for (int mi = 0; mi < 2; ++mi) {
            int rbase = bt0 + w * 32 + mi * 16;
            short8v af[4];
            const short* arow = &G16[(size_t)(rbase + lr) * D];
            #pragma unroll
            for (int ks = 0; ks < 4; ++ks)
                af[ks] = *(const short8v*)&arow[ks * 32 + lg * 8];
            f32x4 acc[8];
            #pragma unroll
            for (int nt = 0; nt < 8; ++nt) acc[nt] = (f32x4){0.f, 0.f, 0.f, 0.f};
            #pragma unroll
            for (int nt = 0; nt < 8; ++nt) {
                #pragma unroll
                for (int ks = 0; ks < 4; ++ks) {
                    short8v bf = *(const short8v*)&Bs[nt * 16 + lr][ks * 32 + lg * 8];
                    acc[nt] = __builtin_amdgcn_mfma_f32_16x16x32_bf16(af[ks], bf, acc[nt], 0, 0, 0);
                }
            }
            int rb = rbase + lg * 4;
            if (rb < BT) {
                float4 fn4 = *(const float4*)&Fn2[rb];
                float fnv[4] = {fn4.x, fn4.y, fn4.z, fn4.w};
                #pragma unroll
                for (int i = 0; i < 4; ++i) {
                    int row = rb + i;
                    int bb = row / T - b_lo;
                    float* orow = out + (size_t)row * N1 + n0;
                    #pragma unroll
                    for (int nt = 0; nt < 8; ++nt) {
                        int cl = nt * 16 + lr;
                        if (n0 + cl < N1) orow[cl] = fnv[i] + in2s[bb][cl] - 2.f * acc[nt][i];
                    }
                }
            }
        }
    }
}

// ---------------- launch ----------------
extern "C" void kernel_launch(void* const* d_in, const int* in_sizes, int n_in,
                              void* d_out, int out_size, void* d_ws, size_t ws_size,
                              hipStream_t stream) {
    const int*   session = (const int*)d_in[0];
    const int*   lengths = (const int*)d_in[1];
    const int*   tau     = (const int*)d_in[2];
    const float* I_emb   = (const float*)d_in[5];
    const float* P_emb   = (const float*)d_in[6];
    const float* EP      = (const float*)d_in[7];
    const float* ES      = (const float*)d_in[8];
    const float* V       = (const float*)d_in[9];
    const float* WP1     = (const float*)d_in[10];
    const float* WP2     = (const float*)d_in[11];
    const float* Wq      = (const float*)d_in[12];
    const float* Wk      = (const float*)d_in[13];
    const float* Wv      = (const float*)d_in[14];
    const float* Wo      = (const float*)d_in[15];
    const float* FF1     = (const float*)d_in[16];
    const float* FF2     = (const float*)d_in[17];
    const float* g1      = (const float*)d_in[18];
    const float* b1      = (const float*)d_in[19];
    const float* g2      = (const float*)d_in[20];
    const float* b2      = (const float*)d_in[21];
    float* out = (float*)d_out;
    float* ws  = (float*)d_ws;

    // workspace layout (floats)
    float* wsX2   = ws;                       // 25600
    float* wsPs   = wsX2 + 25600;             // 4096
    float* wsV    = wsPs + 4096;              // 4096
    float* wsXs   = wsV + 4096;               // 204800 each
    float* wsQ    = wsXs + 204800;
    float* wsK    = wsQ + 204800;
    float* wsVv   = wsK + 204800;
    float* wsFn2  = wsVv + 204800;            // 1600
    float* wsIn2  = wsFn2 + 1600;             // 32*50001 = 1600032
    short* wsG16  = (short*)(wsIn2 + 1600032);            // padded to 1664 rows (212992 shorts)
    unsigned short* wsI16 = (unsigned short*)(wsG16 + 212992);  // 50001*128 shorts

    float* orth_out = out + (size_t)BT * N1;

    k_fused_emb <<<BT, 128, 0, stream>>>(session, lengths, I_emb, EP, ES,
                                         WP1, WP2, Wq, Wk, Wv,
                                         wsX2, wsXs, wsQ, wsK, wsVv);
    k_proxy_head<<<B, 128, 0, stream>>>(wsX2, lengths, tau, P_emb, V, wsPs, wsV, orth_out);
    k_fused_attn<<<BT, 128, 0, stream>>>(session, wsQ, wsK, wsVv, wsXs,
                                         Wo, g1, b1, FF1, FF2, g2, b2,
                                         wsPs, wsV, wsG16, wsFn2);
    k_item_mfma <<<(N1 + 63) / 64, 256, 0, stream>>>(I_emb, wsV, wsIn2, wsI16);
    dim3 gdist((N1 + BN - 1) / BN, 4);
    k_dist_mfma <<<gdist, 256, 0, stream>>>(wsG16, wsI16, wsFn2, wsIn2, out);
}